// Round 2
// baseline (1098.148 us; speedup 1.0000x reference)
//
#include <hip/hip_runtime.h>

// LSTM, S=64 steps, distinct cell per step, bias-free. Persistent kernel,
// 256 WGs x 512 thr (1 WG/CU), flag-based cross-WG step sync.
//
// R3 structural change vs the 903us baseline:
//  - Waves 0-3 are free-running x-GEMM PRODUCERS: x_t @ Wih^T partials go to
//    an 8-deep LDS ring; they stream Wih (268 MB) ahead of the recurrence,
//    gated only by ring space. No __syncthreads in the main loop.
//  - Waves 4-7 are the sequential CONSUMERS: poll flags(t-1) -> h @ Whh^T ->
//    LDS partials -> cell update (tids 256-383) -> publish flag(t).
//  - Half-scope barrier: consumers poll only their own batch-half's 128 flags
//    (the two halves are fully independent).
//  - Single-wave poll: only wave 7 polls (2 cache-bypass loads/lane), then
//    LDS-broadcasts "go". 16x less IFC poll traffic than baseline.
// All intra-WG ordering via LDS sequence counters + explicit s_waitcnt.
// Numeric path (MFMA fragments, cvt, gates) identical to verified baseline.

#define NWG  256
#define NTHR 512

constexpr int S  = 64;
constexpr int NB = 64;     // batch
constexpr int IN = 512;
constexpr int H  = 512;
constexpr int BH = NB * H; // 32768 elements
constexpr int RING = 8;    // x-partial ring depth (steps)

typedef __attribute__((ext_vector_type(8))) short bf16x8;  // 8 bf16 (4 VGPRs)
typedef __attribute__((ext_vector_type(4))) float fx4;

__device__ __forceinline__ short to_bf16(float f) {
  union { float f; unsigned u; } v; v.f = f;
  unsigned r = (v.u + 0x7fffu + ((v.u >> 16) & 1u)) >> 16;  // RNE
  return (short)r;
}
__device__ __forceinline__ bf16x8 cvt8(fx4 a, fx4 b) {
  bf16x8 r;
  r[0] = to_bf16(a[0]); r[1] = to_bf16(a[1]); r[2] = to_bf16(a[2]); r[3] = to_bf16(a[3]);
  r[4] = to_bf16(b[0]); r[5] = to_bf16(b[1]); r[6] = to_bf16(b[2]); r[7] = to_bf16(b[3]);
  return r;
}
// 4 floats via two 8B device-scope (cache-bypassing) atomic loads
__device__ __forceinline__ fx4 ld_h4(const float* p) {
  union { unsigned long long u[2]; fx4 f; } v;
  const unsigned long long* q = (const unsigned long long*)p;
  v.u[0] = __hip_atomic_load(q,     __ATOMIC_RELAXED, __HIP_MEMORY_SCOPE_AGENT);
  v.u[1] = __hip_atomic_load(q + 1, __ATOMIC_RELAXED, __HIP_MEMORY_SCOPE_AGENT);
  return v.f;
}
__device__ __forceinline__ float sigm(float x) { return 1.0f / (1.0f + __expf(-x)); }
__device__ __forceinline__ float tanh_f(float x) { return 2.0f / (1.0f + __expf(-2.0f * x)) - 1.0f; }

__device__ __forceinline__ int lds_ld(const int* p) {
  return __hip_atomic_load(p, __ATOMIC_RELAXED, __HIP_MEMORY_SCOPE_WORKGROUP);
}
__device__ __forceinline__ void lds_st(int* p, int v) {
  __hip_atomic_store(p, v, __ATOMIC_RELAXED, __HIP_MEMORY_SCOPE_WORKGROUP);
}

__global__ void init_flags(int* flags) {
  flags[blockIdx.x * blockDim.x + threadIdx.x] = 0;
}

__global__ void __launch_bounds__(NTHR, 2) lstm_fused(
    const float* __restrict__ x, const float* __restrict__ Wih,
    const float* __restrict__ Whh, float* __restrict__ out,
    float* __restrict__ hbuf, int* __restrict__ flags)
{
  // x-partial ring: [RING][4 waves][32 rows x 16 cols] fp32 = 64 KB
  __shared__ float xring[RING * 4 * 512];
  // h-partial parity buffer: [2][4 waves][512] fp32 = 16 KB
  __shared__ float redh[2 * 4 * 512];
  __shared__ int xfill[4];   // producer wave w has written step (xfill[w]-1)
  __shared__ int hfill[4];   // consumer wave w4 has written step (hfill[w4]-1)
  __shared__ int sfill[2];   // cell wave w4 h-stores drained through step (sfill[w4]-1)
  __shared__ int go_seq;     // wave 7 observed flags through step (go_seq-1)
  __shared__ int cons_seq;   // cell has fully consumed steps < cons_seq

  const int wg   = blockIdx.x;
  const int tid  = threadIdx.x;
  const int wave = tid >> 6;
  const int lane = tid & 63;
  const int cc   = lane & 15;    // MFMA col (gate col) / A-row index
  const int quad = lane >> 4;    // k-subgroup within MFMA
  const int mhalf = wg & 1;      // batch half
  const int n0    = (wg >> 1) << 2;  // 4 h-columns per WG
  // gate-row in W: gate = cc>>2 (i,f,g,o blocks of 512), within = cc&3
  const int jrow  = ((cc >> 2) << 9) + n0 + (cc & 3);
  const int b0    = (mhalf << 5) + cc;   // A row, m-tile 0
  const int b1    = b0 + 16;             // A row, m-tile 1
  const int kq    = ((wave & 3) << 7) + (quad << 3);  // lane k-base within 512
  // partial-store location: row (quad*4+r)*16 + cc, acc1 rows +16 (=+256)
  const int rloc  = (quad << 6) + cc;

  if (tid < 4) { xfill[tid] = 0; hfill[tid] = 0; }
  if (tid < 2) { sfill[tid] = 0; }
  if (tid == 0) { go_seq = 0; cons_seq = 0; }
  __syncthreads();

  if (wave < 4) {
    // ---------------- PRODUCERS: x_t @ Wih^T, free-running ----------------
    const float* wrow = Wih + (size_t)jrow * IN + kq;
    const float* xr0  = x + (size_t)b0 * (S * IN) + kq;
    const float* xr1  = x + (size_t)b1 * (S * IN) + kq;
    fx4 wA[8], wB[8];
    auto load_w = [&](fx4 (&w)[8], int tt) {
      const float* wp = wrow + ((size_t)tt << 20);  // t * 2048 * 512
#pragma unroll
      for (int s2 = 0; s2 < 4; ++s2) {
        w[2 * s2]     = *(const fx4*)(wp + (s2 << 5));
        w[2 * s2 + 1] = *(const fx4*)(wp + (s2 << 5) + 4);
      }
    };
    load_w(wA, 0);

    auto pstep = [&](int t, fx4 (&wc)[8], fx4 (&wn)[8]) {
      if (t + 1 < S) load_w(wn, t + 1);
      if (t >= RING) {  // ring slot t%RING free once step t-RING consumed
        while (lds_ld(&cons_seq) < t - RING + 1) __builtin_amdgcn_s_sleep(1);
        __asm__ volatile("" ::: "memory");
      }
      fx4 acc0 = {0.f, 0.f, 0.f, 0.f}, acc1 = {0.f, 0.f, 0.f, 0.f};
      const float* a0 = xr0 + t * IN;
      const float* a1 = xr1 + t * IN;
#pragma unroll
      for (int s2 = 0; s2 < 4; ++s2) {
        bf16x8 wf  = cvt8(wc[2 * s2], wc[2 * s2 + 1]);
        bf16x8 af0 = cvt8(*(const fx4*)(a0 + (s2 << 5)), *(const fx4*)(a0 + (s2 << 5) + 4));
        bf16x8 af1 = cvt8(*(const fx4*)(a1 + (s2 << 5)), *(const fx4*)(a1 + (s2 << 5) + 4));
        acc0 = __builtin_amdgcn_mfma_f32_16x16x32_bf16(af0, wf, acc0, 0, 0, 0);
        acc1 = __builtin_amdgcn_mfma_f32_16x16x32_bf16(af1, wf, acc1, 0, 0, 0);
      }
      float* dst = xring + ((t & (RING - 1)) << 11) + (wave << 9) + rloc;
#pragma unroll
      for (int r = 0; r < 4; ++r) {
        dst[r << 4]         = acc0[r];
        dst[(r << 4) + 256] = acc1[r];
      }
      __asm__ volatile("s_waitcnt lgkmcnt(0)" ::: "memory");
      if (lane == 0) lds_st(&xfill[wave], t + 1);
    };
#pragma unroll 1
    for (int t = 0; t < S; t += 2) { pstep(t, wA, wB); pstep(t + 1, wB, wA); }

  } else {
    // ---------------- CONSUMERS: recurrence h @ Whh^T + cell --------------
    const float* wrow = Whh + (size_t)jrow * IN + kq;
    const float* hr0  = hbuf + (size_t)b0 * H + kq;
    const float* hr1  = hbuf + (size_t)b1 * H + kq;
    const int w4 = wave - 4;
    const int ct = tid - 256;              // 0..255
    const int cm = ct >> 2, cn = ct & 3;   // cell mapping (ct < 128)
    const int ob = (mhalf << 5) + cm, ocol = n0 + cn;
    const bool is_cell = (ct < 128);       // waves 4,5
    float c_state = 0.f;

    fx4 wA[8], wB[8];
    auto load_w = [&](fx4 (&w)[8], int tt) {
      const float* wp = wrow + ((size_t)tt << 20);
#pragma unroll
      for (int s2 = 0; s2 < 4; ++s2) {
        w[2 * s2]     = *(const fx4*)(wp + (s2 << 5));
        w[2 * s2 + 1] = *(const fx4*)(wp + (s2 << 5) + 4);
      }
    };
    // no initial load: Whh is first used at t=1, prefetched during t=0

    auto cstep = [&](int t, fx4 (&wc)[8], fx4 (&wn)[8]) {
      if (t + 1 < S) load_w(wn, t + 1);  // Whh(t+1) streams during poll window
      fx4 acc0 = {0.f, 0.f, 0.f, 0.f}, acc1 = {0.f, 0.f, 0.f, 0.f};
      if (t > 0) {
        if (wave == 7) {
          // poll own half's 128 flags for step t-1 (wg parity == mhalf)
          const int* fl = flags + ((t - 1) << 8) + mhalf;
          while (true) {
            int f0 = __hip_atomic_load(fl + (lane << 1),        __ATOMIC_RELAXED, __HIP_MEMORY_SCOPE_AGENT);
            int f1 = __hip_atomic_load(fl + ((lane + 64) << 1), __ATOMIC_RELAXED, __HIP_MEMORY_SCOPE_AGENT);
            if (__ballot((f0 & f1) != 0) == ~0ull) break;
            __builtin_amdgcn_s_sleep(2);
          }
          __asm__ volatile("" ::: "memory");
          if (lane == 0) lds_st(&go_seq, t);
        } else {
          while (lds_ld(&go_seq) < t) __builtin_amdgcn_s_sleep(1);
          __asm__ volatile("" ::: "memory");
        }
        const float* h0 = hr0 + (size_t)(t & 1) * BH;
        const float* h1 = hr1 + (size_t)(t & 1) * BH;
#pragma unroll
        for (int s2 = 0; s2 < 4; ++s2) {
          bf16x8 wf  = cvt8(wc[2 * s2], wc[2 * s2 + 1]);
          bf16x8 af0 = cvt8(ld_h4(h0 + (s2 << 5)), ld_h4(h0 + (s2 << 5) + 4));
          bf16x8 af1 = cvt8(ld_h4(h1 + (s2 << 5)), ld_h4(h1 + (s2 << 5) + 4));
          acc0 = __builtin_amdgcn_mfma_f32_16x16x32_bf16(af0, wf, acc0, 0, 0, 0);
          acc1 = __builtin_amdgcn_mfma_f32_16x16x32_bf16(af1, wf, acc1, 0, 0, 0);
        }
      }
      // redh[t&1] free once step t-2 consumed
      if (t >= 2) {
        while (lds_ld(&cons_seq) < t - 1) __builtin_amdgcn_s_sleep(1);
        __asm__ volatile("" ::: "memory");
      }
      float* dst = redh + ((t & 1) << 11) + (w4 << 9) + rloc;
#pragma unroll
      for (int r = 0; r < 4; ++r) {
        dst[r << 4]         = acc0[r];
        dst[(r << 4) + 256] = acc1[r];
      }
      __asm__ volatile("s_waitcnt lgkmcnt(0)" ::: "memory");
      if (lane == 0) lds_st(&hfill[w4], t + 1);

      if (is_cell) {
        for (;;) {
          bool ok = true;
#pragma unroll
          for (int w = 0; w < 4; ++w) {
            ok &= lds_ld(&xfill[w]) >= t + 1;
            ok &= lds_ld(&hfill[w]) >= t + 1;
          }
          if (ok) break;
          __builtin_amdgcn_s_sleep(1);
        }
        __asm__ volatile("" ::: "memory");
        const float* xs = xring + ((t & (RING - 1)) << 11);
        const float* hs = redh + ((t & 1) << 11);
        const int o = (cm << 4) + cn;
        float gv[4];
#pragma unroll
        for (int g = 0; g < 4; ++g) {
          float s = 0.f;
          const int oo = o + (g << 2);
#pragma unroll
          for (int w = 0; w < 4; ++w)
            s += xs[(w << 9) + oo] + hs[(w << 9) + oo];
          gv[g] = s;
        }
        float ig = sigm(gv[0]);
        float fg = sigm(gv[1]);
        float gg = tanh_f(gv[2]);
        float og = sigm(gv[3]);
        c_state  = fg * c_state + ig * gg;
        float h  = og * tanh_f(c_state);
        out[((size_t)ob * S + t) * H + ocol] = h;
        __hip_atomic_store(hbuf + (size_t)((t + 1) & 1) * BH + (size_t)ob * H + ocol,
                           h, __ATOMIC_RELAXED, __HIP_MEMORY_SCOPE_AGENT);
        __asm__ volatile("s_waitcnt vmcnt(0)" ::: "memory");  // h stores at IFC
        if (lane == 0) lds_st(&sfill[w4], t + 1);
        if (tid == 256) {
          while (lds_ld(&sfill[1]) < t + 1) __builtin_amdgcn_s_sleep(1);
          __hip_atomic_store(flags + (t << 8) + wg, 1, __ATOMIC_RELAXED, __HIP_MEMORY_SCOPE_AGENT);
          lds_st(&cons_seq, t + 1);
        }
      }
    };
#pragma unroll 1
    for (int t = 0; t < S; t += 2) { cstep(t, wA, wB); cstep(t + 1, wB, wA); }
  }
}

extern "C" void kernel_launch(void* const* d_in, const int* in_sizes, int n_in,
                              void* d_out, int out_size, void* d_ws, size_t ws_size,
                              hipStream_t stream) {
  const float* x   = (const float*)d_in[0];
  const float* Wih = (const float*)d_in[1];
  const float* Whh = (const float*)d_in[2];
  float* out = (float*)d_out;

  // ws layout: [0,256K) h double-buffer (fp32 2*64*512), [256K,320K) flags[64][256]
  float* hbuf = (float*)d_ws;
  int* flags  = (int*)((char*)d_ws + (size_t)2 * BH * sizeof(float));

  hipLaunchKernelGGL(init_flags, dim3(64), dim3(256), 0, stream, flags);  // 16384 ints
  hipLaunchKernelGGL(lstm_fused, dim3(NWG), dim3(NTHR), 0, stream,
                     x, Wih, Whh, out, hbuf, flags);
}